// Round 1
// baseline (160.939 us; speedup 1.0000x reference)
//
#include <hip/hip_runtime.h>
#include <hip/hip_bf16.h>
#include <math.h>

#define NTOK 512
#define DIN  1024
#define NQKVO 4096
#define NHEAD 8
#define DHEAD 128
#define KSCALE 0.08838834764831845f  // 1/sqrt(128)

typedef __bf16 bf16x8 __attribute__((ext_vector_type(8)));
typedef float  f32x4  __attribute__((ext_vector_type(4)));
typedef unsigned short u16x4 __attribute__((ext_vector_type(4)));
typedef unsigned short u16x8 __attribute__((ext_vector_type(8)));

__device__ inline unsigned short f2bf(float f) {
    unsigned int u = __float_as_uint(f);
    unsigned int r = (u + 0x7FFFu + ((u >> 16) & 1u)) >> 16;
    return (unsigned short)r;
}

// ---- K0a: x (f32) -> bf16, 512*1024 elems, 4/thread -------------------------
__global__ __launch_bounds__(256) void convert_x(const float* __restrict__ x,
                                                 unsigned short* __restrict__ xb) {
    int t = blockIdx.x * 256 + threadIdx.x;           // 0..131071
    float4 v = reinterpret_cast<const float4*>(x)[t];
    u16x4 o = { f2bf(v.x), f2bf(v.y), f2bf(v.z), f2bf(v.w) };
    reinterpret_cast<u16x4*>(xb)[t] = o;
}

// ---- K0b: W [1024][4096] f32 -> Wt [4096][1024] bf16 (transpose) ------------
__global__ __launch_bounds__(256) void transpose_w(const float* __restrict__ W,
                                                   unsigned short* __restrict__ Wt) {
    __shared__ float tile[32][33];
    int bk = blockIdx.x & 31;       // 1024/32
    int bn = blockIdx.x >> 5;       // 4096/32
    int k0 = bk * 32, n0 = bn * 32;
    int r = threadIdx.x >> 5, col = threadIdx.x & 31;
#pragma unroll
    for (int it = 0; it < 4; ++it)
        tile[r + it * 8][col] = W[(size_t)(k0 + r + it * 8) * 4096 + n0 + col];
    __syncthreads();
#pragma unroll
    for (int it = 0; it < 4; ++it)
        Wt[(size_t)(n0 + r + it * 8) * 1024 + k0 + col] = f2bf(tile[col][r + it * 8]);
}

// ---- K1: qkvo = x @ W + b   (bf16 MFMA, f32 accum) --------------------------
// A: xb [512][1024] bf16 (row-major, K contig). B: Wt [4096][1024] (N rows, K contig).
__global__ __launch_bounds__(256) void gemm_qkvo(const unsigned short* __restrict__ A,
                                                 const unsigned short* __restrict__ Bt,
                                                 const float* __restrict__ bias,
                                                 float* __restrict__ C) {
    __shared__ __align__(16) unsigned short As[64][72];
    __shared__ __align__(16) unsigned short Bs[64][72];
    const int bm = blockIdx.x & 7;          // 512/64 M tiles
    const int bn = blockIdx.x >> 3;         // 4096/64 N tiles
    const int m0 = bm * 64, n0 = bn * 64;
    const int tid = threadIdx.x;
    const int lane = tid & 63, wave = tid >> 6;
    const int wr = wave >> 1, wc = wave & 1;     // 2x2 waves, each 32x32 out
    f32x4 acc[2][2] = {};

    for (int k0 = 0; k0 < 1024; k0 += 64) {
#pragma unroll
        for (int c = 0; c < 2; ++c) {
            int chunk = tid + c * 256;           // 0..511
            int r = chunk >> 3, col = (chunk & 7) * 8;
            *reinterpret_cast<u16x8*>(&As[r][col]) =
                *reinterpret_cast<const u16x8*>(&A[(size_t)(m0 + r) * 1024 + k0 + col]);
            *reinterpret_cast<u16x8*>(&Bs[r][col]) =
                *reinterpret_cast<const u16x8*>(&Bt[(size_t)(n0 + r) * 1024 + k0 + col]);
        }
        __syncthreads();
        const int row = lane & 15;
        const int kof = (lane >> 4) * 8;
#pragma unroll
        for (int kk = 0; kk < 2; ++kk) {
            int kb = kk * 32 + kof;
            bf16x8 a0 = *reinterpret_cast<const bf16x8*>(&As[wr * 32 + row][kb]);
            bf16x8 a1 = *reinterpret_cast<const bf16x8*>(&As[wr * 32 + 16 + row][kb]);
            bf16x8 b0 = *reinterpret_cast<const bf16x8*>(&Bs[wc * 32 + row][kb]);
            bf16x8 b1 = *reinterpret_cast<const bf16x8*>(&Bs[wc * 32 + 16 + row][kb]);
            acc[0][0] = __builtin_amdgcn_mfma_f32_16x16x32_bf16(a0, b0, acc[0][0], 0, 0, 0);
            acc[0][1] = __builtin_amdgcn_mfma_f32_16x16x32_bf16(a0, b1, acc[0][1], 0, 0, 0);
            acc[1][0] = __builtin_amdgcn_mfma_f32_16x16x32_bf16(a1, b0, acc[1][0], 0, 0, 0);
            acc[1][1] = __builtin_amdgcn_mfma_f32_16x16x32_bf16(a1, b1, acc[1][1], 0, 0, 0);
        }
        __syncthreads();
    }
    // D: col = lane&15, row = (lane>>4)*4 + v   [verified m89/m91]
    const int cn = lane & 15, cm = (lane >> 4) * 4;
#pragma unroll
    for (int i = 0; i < 2; ++i)
#pragma unroll
        for (int j = 0; j < 2; ++j) {
            int gm = m0 + wr * 32 + i * 16 + cm;
            int gn = n0 + wc * 32 + j * 16 + cn;
            float b = bias[gn];
#pragma unroll
            for (int v = 0; v < 4; ++v)
                C[(size_t)(gm + v) * 4096 + gn] = acc[i][j][v] + b;
        }
}

// ---- K1b: u,f gates (f32 exact) ---------------------------------------------
// fe_ue[(h*512+n)*2 + {0,1}] = {fe, ue}
__global__ __launch_bounds__(64) void uf_gates(const float* __restrict__ x,
                                               const float* __restrict__ Wuf,
                                               const float* __restrict__ buf,
                                               const float* __restrict__ m_prev,
                                               float* __restrict__ fe_ue) {
    int n = blockIdx.x, lane = threadIdx.x;
    float p[16];
#pragma unroll
    for (int c = 0; c < 16; ++c) p[c] = 0.f;
    for (int k = lane; k < 1024; k += 64) {
        float xv = x[(size_t)n * 1024 + k];
#pragma unroll
        for (int c = 0; c < 16; ++c) p[c] += xv * Wuf[k * 16 + c];
    }
#pragma unroll
    for (int c = 0; c < 16; ++c) {
        float v = p[c];
#pragma unroll
        for (int off = 32; off; off >>= 1) v += __shfl_down(v, off);
        p[c] = v;
    }
    if (lane == 0) {
#pragma unroll
        for (int h = 0; h < 8; ++h) {
            float u = p[2 * h] + buf[2 * h];
            float f = p[2 * h + 1] + buf[2 * h + 1];
            float mp = m_prev[h * 512 + n];
            float m = fmaxf(f + mp, u);
            float ue = expf(u - m);
            float fe = expf(f + mp - m);
            fe_ue[(h * 512 + n) * 2 + 0] = fe;
            fe_ue[(h * 512 + n) * 2 + 1] = ue;
        }
    }
}

// ---- K2: per-(h,n) fused: gates, h-head, c_new stream -----------------------
__global__ __launch_bounds__(256) void fuse_main(const float* __restrict__ qkvo,
                                                 const float* __restrict__ c_in,
                                                 const float* __restrict__ n_prev,
                                                 const float* __restrict__ fe_ue,
                                                 float* __restrict__ c_out,
                                                 float* __restrict__ hst) {
    const int blk = blockIdx.x;             // 0..4095
    const int h = blk >> 9, n = blk & 511;
    const int tid = threadIdx.x;
    __shared__ float k_s[128], v_s[128];
    __shared__ float rkq[4], rnq[4];

    const float* base = qkvo + (size_t)n * 4096 + h * 512;
    const float fe = fe_ue[(h * 512 + n) * 2 + 0];
    const float ue = fe_ue[(h * 512 + n) * 2 + 1];

    float kq_p = 0.f, nq_p = 0.f;
    if (tid < 128) {
        float q = base[tid];
        float k = base[128 + tid] * KSCALE;
        float v = base[256 + tid];
        k_s[tid] = k;
        v_s[tid] = v;
        float nn = fe * n_prev[(size_t)(h * 512 + n) * 128 + tid] + ue * k;
        kq_p = k * q;
        nq_p = nn * q;
    }
#pragma unroll
    for (int off = 32; off; off >>= 1) {
        kq_p += __shfl_down(kq_p, off);
        nq_p += __shfl_down(nq_p, off);
    }
    if ((tid & 63) == 0) { rkq[tid >> 6] = kq_p; rnq[tid >> 6] = nq_p; }
    __syncthreads();
    const float kq = rkq[0] + rkq[1];
    const float nm = fabsf(rnq[0] + rnq[1]);
    const float g = kq / fmaxf(nm, 1.0f);

    // stream c: 16384 f32 = 4096 float4; 16 per thread
    const float4* cin4 = reinterpret_cast<const float4*>(c_in + (size_t)(h * 512 + n) * 16384);
    float4* cout4 = reinterpret_cast<float4*>(c_out + (size_t)(h * 512 + n) * 16384);
#pragma unroll
    for (int it = 0; it < 16; ++it) {
        int e4 = tid + it * 256;
        int i = e4 >> 5;
        int j4 = (e4 & 31) * 4;
        float4 cv = cin4[e4];
        float uv = ue * v_s[i];
        float4 o;
        o.x = fe * cv.x + uv * k_s[j4 + 0];
        o.y = fe * cv.y + uv * k_s[j4 + 1];
        o.z = fe * cv.z + uv * k_s[j4 + 2];
        o.w = fe * cv.w + uv * k_s[j4 + 3];
        cout4[e4] = o;
    }

    if (tid < 128) {
        float o = base[384 + tid];
        float sig = 1.f / (1.f + expf(-o));
        hst[(size_t)n * 1024 + h * 128 + tid] = v_s[tid] * g * sig;
    }
}

// ---- K3: residual + LayerNorm -----------------------------------------------
__global__ __launch_bounds__(256) void ln_kernel(const float* __restrict__ x,
                                                 const float* __restrict__ hst,
                                                 float* __restrict__ out) {
    int n = blockIdx.x, tid = threadIdx.x;
    float4 hv = reinterpret_cast<const float4*>(hst + (size_t)n * 1024)[tid];
    float4 xv = reinterpret_cast<const float4*>(x + (size_t)n * 1024)[tid];
    float4 s = { hv.x + xv.x, hv.y + xv.y, hv.z + xv.z, hv.w + xv.w };
    float sum = s.x + s.y + s.z + s.w;
    float sq = s.x * s.x + s.y * s.y + s.z * s.z + s.w * s.w;
#pragma unroll
    for (int off = 32; off; off >>= 1) {
        sum += __shfl_down(sum, off);
        sq += __shfl_down(sq, off);
    }
    __shared__ float rs[4], rq[4];
    if ((tid & 63) == 0) { rs[tid >> 6] = sum; rq[tid >> 6] = sq; }
    __syncthreads();
    sum = rs[0] + rs[1] + rs[2] + rs[3];
    sq = rq[0] + rq[1] + rq[2] + rq[3];
    float mu = sum * (1.f / 1024.f);
    float var = sq * (1.f / 1024.f) - mu * mu;
    float inv = rsqrtf(var + 1e-5f);
    float4 o4 = { (s.x - mu) * inv, (s.y - mu) * inv, (s.z - mu) * inv, (s.w - mu) * inv };
    reinterpret_cast<float4*>(out)[(size_t)n * 256 + tid] = o4;
}

extern "C" void kernel_launch(void* const* d_in, const int* in_sizes, int n_in,
                              void* d_out, int out_size, void* d_ws, size_t ws_size,
                              hipStream_t stream) {
    const float* x      = (const float*)d_in[0];
    const float* c_in   = (const float*)d_in[1];
    const float* m_prev = (const float*)d_in[2];
    const float* n_prev = (const float*)d_in[3];
    const float* Wqkvo  = (const float*)d_in[4];
    const float* bqkvo  = (const float*)d_in[5];
    const float* Wuf    = (const float*)d_in[6];
    const float* buf    = (const float*)d_in[7];
    float* out = (float*)d_out;
    char* ws = (char*)d_ws;

    unsigned short* xb   = (unsigned short*)(ws);                    // 1 MB
    unsigned short* Wt   = (unsigned short*)(ws + (1u << 20));       // 8 MB
    float* qkvo          = (float*)(ws + 9u * (1u << 20));           // 8 MB
    float* fe_ue         = (float*)(ws + 17u * (1u << 20));          // 32 KB
    float* hst           = (float*)(ws + 17u * (1u << 20) + (1u << 16)); // 2 MB

    convert_x  <<<dim3(512),  dim3(256), 0, stream>>>(x, xb);
    transpose_w<<<dim3(4096), dim3(256), 0, stream>>>(Wqkvo, Wt);
    gemm_qkvo  <<<dim3(512),  dim3(256), 0, stream>>>(xb, Wt, bqkvo, qkvo);
    uf_gates   <<<dim3(512),  dim3(64),  0, stream>>>(x, Wuf, buf, m_prev, fe_ue);
    fuse_main  <<<dim3(4096), dim3(256), 0, stream>>>(qkvo, c_in, n_prev, fe_ue, out, hst);
    ln_kernel  <<<dim3(512),  dim3(256), 0, stream>>>(x, hst, out + 67108864ull);
}

// Round 3
// 142.414 us; speedup vs baseline: 1.1301x; 1.1301x over previous
//
#include <hip/hip_runtime.h>
#include <hip/hip_bf16.h>
#include <math.h>

#define KSCALE 0.08838834764831845f  // 1/sqrt(128)

typedef __bf16 bf16x8 __attribute__((ext_vector_type(8)));
typedef float  f32x4  __attribute__((ext_vector_type(4)));
typedef unsigned short u16x4 __attribute__((ext_vector_type(4)));
typedef unsigned short u16x8 __attribute__((ext_vector_type(8)));

__device__ inline unsigned short f2bf(float f) {
    unsigned int u = __float_as_uint(f);
    unsigned int r = (u + 0x7FFFu + ((u >> 16) & 1u)) >> 16;
    return (unsigned short)r;
}

// ---- K0: fused prep: x->bf16 (blocks 0..511), W transpose+convert (512..4607)
__global__ __launch_bounds__(256) void prep_kernel(const float* __restrict__ x,
                                                   unsigned short* __restrict__ xb,
                                                   const float* __restrict__ W,
                                                   unsigned short* __restrict__ Wt) {
    int b = blockIdx.x;
    if (b < 512) {
        int t = b * 256 + threadIdx.x;            // 131072 float4s
        float4 v = reinterpret_cast<const float4*>(x)[t];
        u16x4 o = { f2bf(v.x), f2bf(v.y), f2bf(v.z), f2bf(v.w) };
        reinterpret_cast<u16x4*>(xb)[t] = o;
    } else {
        __shared__ float tile[32][33];
        int bb = b - 512;
        int bk = bb & 31;        // 1024/32
        int bn = bb >> 5;        // 4096/32
        int k0 = bk * 32, n0 = bn * 32;
        int r = threadIdx.x >> 5, col = threadIdx.x & 31;
#pragma unroll
        for (int it = 0; it < 4; ++it)
            tile[r + it * 8][col] = W[(size_t)(k0 + r + it * 8) * 4096 + n0 + col];
        __syncthreads();
#pragma unroll
        for (int it = 0; it < 4; ++it)
            Wt[(size_t)(n0 + r + it * 8) * 1024 + k0 + col] = f2bf(tile[col][r + it * 8]);
    }
}

// ---- K1: qkvo = x @ W + b   (bf16 MFMA, f32 accum), 64x64 tile --------------
__global__ __launch_bounds__(256) void gemm_qkvo(const unsigned short* __restrict__ A,
                                                 const unsigned short* __restrict__ Bt,
                                                 const float* __restrict__ bias,
                                                 float* __restrict__ C) {
    __shared__ __align__(16) unsigned short As[64][72];
    __shared__ __align__(16) unsigned short Bs[64][72];
    const int bm = blockIdx.x & 7;          // 512/64 M tiles
    const int bn = blockIdx.x >> 3;         // 4096/64 N tiles
    const int m0 = bm * 64, n0 = bn * 64;
    const int tid = threadIdx.x;
    const int lane = tid & 63, wave = tid >> 6;
    const int wr = wave >> 1, wc = wave & 1;     // 2x2 waves, each 32x32 out
    f32x4 acc[2][2] = {};

    for (int k0 = 0; k0 < 1024; k0 += 64) {
#pragma unroll
        for (int c = 0; c < 2; ++c) {
            int chunk = tid + c * 256;           // 0..511
            int r = chunk >> 3, col = (chunk & 7) * 8;
            *reinterpret_cast<u16x8*>(&As[r][col]) =
                *reinterpret_cast<const u16x8*>(&A[(size_t)(m0 + r) * 1024 + k0 + col]);
            *reinterpret_cast<u16x8*>(&Bs[r][col]) =
                *reinterpret_cast<const u16x8*>(&Bt[(size_t)(n0 + r) * 1024 + k0 + col]);
        }
        __syncthreads();
        const int row = lane & 15;
        const int kof = (lane >> 4) * 8;
#pragma unroll
        for (int kk = 0; kk < 2; ++kk) {
            int kb = kk * 32 + kof;
            bf16x8 a0 = *reinterpret_cast<const bf16x8*>(&As[wr * 32 + row][kb]);
            bf16x8 a1 = *reinterpret_cast<const bf16x8*>(&As[wr * 32 + 16 + row][kb]);
            bf16x8 b0 = *reinterpret_cast<const bf16x8*>(&Bs[wc * 32 + row][kb]);
            bf16x8 b1 = *reinterpret_cast<const bf16x8*>(&Bs[wc * 32 + 16 + row][kb]);
            acc[0][0] = __builtin_amdgcn_mfma_f32_16x16x32_bf16(a0, b0, acc[0][0], 0, 0, 0);
            acc[0][1] = __builtin_amdgcn_mfma_f32_16x16x32_bf16(a0, b1, acc[0][1], 0, 0, 0);
            acc[1][0] = __builtin_amdgcn_mfma_f32_16x16x32_bf16(a1, b0, acc[1][0], 0, 0, 0);
            acc[1][1] = __builtin_amdgcn_mfma_f32_16x16x32_bf16(a1, b1, acc[1][1], 0, 0, 0);
        }
        __syncthreads();
    }
    const int cn = lane & 15, cm = (lane >> 4) * 4;
#pragma unroll
    for (int i = 0; i < 2; ++i)
#pragma unroll
        for (int j = 0; j < 2; ++j) {
            int gm = m0 + wr * 32 + i * 16 + cm;
            int gn = n0 + wc * 32 + j * 16 + cn;
            float b = bias[gn];
#pragma unroll
            for (int v = 0; v < 4; ++v)
                C[(size_t)(gm + v) * 4096 + gn] = acc[i][j][v] + b;
        }
}

// ---- K1b: u,f gates (f32 exact). 256 thr/block: wave w owns cols 4w..4w+3 ----
__global__ __launch_bounds__(256) void uf_gates(const float* __restrict__ x,
                                                const float* __restrict__ Wuf,
                                                const float* __restrict__ buf,
                                                const float* __restrict__ m_prev,
                                                float* __restrict__ fe_ue) {
    const int n = blockIdx.x;
    const int tid = threadIdx.x;
    const int lane = tid & 63, w = tid >> 6;
    const float* xr = x + (size_t)n * 1024;
    float4 p = {0.f, 0.f, 0.f, 0.f};
#pragma unroll
    for (int i = 0; i < 16; ++i) {
        int k = lane + i * 64;
        float xv = xr[k];
        float4 wv = *reinterpret_cast<const float4*>(&Wuf[(size_t)k * 16 + 4 * w]);
        p.x += xv * wv.x; p.y += xv * wv.y; p.z += xv * wv.z; p.w += xv * wv.w;
    }
#pragma unroll
    for (int off = 32; off; off >>= 1) {
        p.x += __shfl_down(p.x, off);
        p.y += __shfl_down(p.y, off);
        p.z += __shfl_down(p.z, off);
        p.w += __shfl_down(p.w, off);
    }
    if (lane == 0) {
#pragma unroll
        for (int t = 0; t < 2; ++t) {
            int h = 2 * w + t;
            float u = (t ? p.z : p.x) + buf[4 * w + 2 * t];
            float f = (t ? p.w : p.y) + buf[4 * w + 2 * t + 1];
            float mp = m_prev[h * 512 + n];
            float m = fmaxf(f + mp, u);
            fe_ue[(h * 512 + n) * 2 + 0] = expf(f + mp - m);
            fe_ue[(h * 512 + n) * 2 + 1] = expf(u - m);
        }
    }
}

// ---- K2: per-(h,n) fused: gates, h-head, c_new stream (non-temporal) --------
__global__ __launch_bounds__(256) void fuse_main(const float* __restrict__ qkvo,
                                                 const float* __restrict__ c_in,
                                                 const float* __restrict__ n_prev,
                                                 const float* __restrict__ fe_ue,
                                                 float* __restrict__ c_out,
                                                 float* __restrict__ hst) {
    const int blk = blockIdx.x;             // 0..4095
    const int h = blk >> 9, n = blk & 511;
    const int tid = threadIdx.x;
    __shared__ float k_s[128], v_s[128];
    __shared__ float rkq[4], rnq[4];

    const float* base = qkvo + (size_t)n * 4096 + h * 512;
    const float fe = fe_ue[(h * 512 + n) * 2 + 0];
    const float ue = fe_ue[(h * 512 + n) * 2 + 1];

    float kq_p = 0.f, nq_p = 0.f;
    if (tid < 128) {
        float q = base[tid];
        float k = base[128 + tid] * KSCALE;
        float v = base[256 + tid];
        k_s[tid] = k;
        v_s[tid] = v;
        float nn = fe * n_prev[(size_t)(h * 512 + n) * 128 + tid] + ue * k;
        kq_p = k * q;
        nq_p = nn * q;
    }
#pragma unroll
    for (int off = 32; off; off >>= 1) {
        kq_p += __shfl_down(kq_p, off);
        nq_p += __shfl_down(nq_p, off);
    }
    if ((tid & 63) == 0) { rkq[tid >> 6] = kq_p; rnq[tid >> 6] = nq_p; }
    __syncthreads();
    const float kq = rkq[0] + rkq[1];
    const float nm = fabsf(rnq[0] + rnq[1]);
    const float g = kq / fmaxf(nm, 1.0f);

    // stream c: 16384 f32 = 4096 f32x4; 16 per thread, non-temporal
    const f32x4* cin4 = reinterpret_cast<const f32x4*>(c_in + (size_t)(h * 512 + n) * 16384);
    f32x4* cout4 = reinterpret_cast<f32x4*>(c_out + (size_t)(h * 512 + n) * 16384);
#pragma unroll
    for (int it = 0; it < 16; ++it) {
        int e4 = tid + it * 256;
        int i = e4 >> 5;
        int j4 = (e4 & 31) * 4;
        f32x4 cv = __builtin_nontemporal_load(&cin4[e4]);
        float uv = ue * v_s[i];
        f32x4 o;
        o.x = fe * cv.x + uv * k_s[j4 + 0];
        o.y = fe * cv.y + uv * k_s[j4 + 1];
        o.z = fe * cv.z + uv * k_s[j4 + 2];
        o.w = fe * cv.w + uv * k_s[j4 + 3];
        __builtin_nontemporal_store(o, &cout4[e4]);
    }

    if (tid < 128) {
        float o = base[384 + tid];
        float sig = 1.f / (1.f + expf(-o));
        hst[(size_t)n * 1024 + h * 128 + tid] = v_s[tid] * g * sig;
    }
}

// ---- K3: residual + LayerNorm -----------------------------------------------
__global__ __launch_bounds__(256) void ln_kernel(const float* __restrict__ x,
                                                 const float* __restrict__ hst,
                                                 float* __restrict__ out) {
    int n = blockIdx.x, tid = threadIdx.x;
    float4 hv = reinterpret_cast<const float4*>(hst + (size_t)n * 1024)[tid];
    float4 xv = reinterpret_cast<const float4*>(x + (size_t)n * 1024)[tid];
    float4 s = { hv.x + xv.x, hv.y + xv.y, hv.z + xv.z, hv.w + xv.w };
    float sum = s.x + s.y + s.z + s.w;
    float sq = s.x * s.x + s.y * s.y + s.z * s.z + s.w * s.w;
#pragma unroll
    for (int off = 32; off; off >>= 1) {
        sum += __shfl_down(sum, off);
        sq += __shfl_down(sq, off);
    }
    __shared__ float rs[4], rq[4];
    if ((tid & 63) == 0) { rs[tid >> 6] = sum; rq[tid >> 6] = sq; }
    __syncthreads();
    sum = rs[0] + rs[1] + rs[2] + rs[3];
    sq = rq[0] + rq[1] + rq[2] + rq[3];
    float mu = sum * (1.f / 1024.f);
    float var = sq * (1.f / 1024.f) - mu * mu;
    float inv = rsqrtf(var + 1e-5f);
    float4 o4 = { (s.x - mu) * inv, (s.y - mu) * inv, (s.z - mu) * inv, (s.w - mu) * inv };
    reinterpret_cast<float4*>(out)[(size_t)n * 256 + tid] = o4;
}

extern "C" void kernel_launch(void* const* d_in, const int* in_sizes, int n_in,
                              void* d_out, int out_size, void* d_ws, size_t ws_size,
                              hipStream_t stream) {
    const float* x      = (const float*)d_in[0];
    const float* c_in   = (const float*)d_in[1];
    const float* m_prev = (const float*)d_in[2];
    const float* n_prev = (const float*)d_in[3];
    const float* Wqkvo  = (const float*)d_in[4];
    const float* bqkvo  = (const float*)d_in[5];
    const float* Wuf    = (const float*)d_in[6];
    const float* buf    = (const float*)d_in[7];
    float* out = (float*)d_out;
    char* ws = (char*)d_ws;

    unsigned short* xb   = (unsigned short*)(ws);                        // 1 MB
    unsigned short* Wt   = (unsigned short*)(ws + (1u << 20));           // 8 MB
    float* qkvo          = (float*)(ws + 9u * (1u << 20));               // 8 MB
    float* fe_ue         = (float*)(ws + 17u * (1u << 20));              // 32 KB
    float* hst           = (float*)(ws + 17u * (1u << 20) + (1u << 16)); // 2 MB

    prep_kernel<<<dim3(4608), dim3(256), 0, stream>>>(x, xb, Wqkvo, Wt);
    uf_gates   <<<dim3(512),  dim3(256), 0, stream>>>(x, Wuf, buf, m_prev, fe_ue);
    gemm_qkvo  <<<dim3(512),  dim3(256), 0, stream>>>(xb, Wt, bqkvo, qkvo);
    fuse_main  <<<dim3(4096), dim3(256), 0, stream>>>(qkvo, c_in, n_prev, fe_ue, out, hst);
    ln_kernel  <<<dim3(512),  dim3(256), 0, stream>>>(x, hst, out + 67108864ull);
}

// Round 4
// 136.600 us; speedup vs baseline: 1.1782x; 1.0426x over previous
//
#include <hip/hip_runtime.h>
#include <hip/hip_bf16.h>
#include <math.h>

#define KSCALE 0.08838834764831845f  // 1/sqrt(128)

typedef __bf16 bf16x8 __attribute__((ext_vector_type(8)));
typedef float  f32x4  __attribute__((ext_vector_type(4)));
typedef unsigned short u16x4 __attribute__((ext_vector_type(4)));
typedef unsigned short u16x8 __attribute__((ext_vector_type(8)));

__device__ inline unsigned short f2bf(float f) {
    unsigned int u = __float_as_uint(f);
    unsigned int r = (u + 0x7FFFu + ((u >> 16) & 1u)) >> 16;
    return (unsigned short)r;
}

// async global->LDS, 16B per lane; lds dest must be wave-uniform base (+lane*16)
__device__ __forceinline__ void gll16(const unsigned short* g, unsigned short* l) {
    __builtin_amdgcn_global_load_lds(
        (const __attribute__((address_space(1))) unsigned int*)g,
        (__attribute__((address_space(3))) unsigned int*)l,
        16, 0, 0);
}

// ---- K0: fused prep: x->bf16 (0..511), W transpose (512..4607), uf (4608..5119)
__global__ __launch_bounds__(256) void prep_kernel(const float* __restrict__ x,
                                                   unsigned short* __restrict__ xb,
                                                   const float* __restrict__ W,
                                                   unsigned short* __restrict__ Wt,
                                                   const float* __restrict__ Wuf,
                                                   const float* __restrict__ buf,
                                                   const float* __restrict__ m_prev,
                                                   float* __restrict__ fe_ue) {
    int b = blockIdx.x;
    if (b < 512) {
        int t = b * 256 + threadIdx.x;            // 131072 float4s
        float4 v = reinterpret_cast<const float4*>(x)[t];
        u16x4 o = { f2bf(v.x), f2bf(v.y), f2bf(v.z), f2bf(v.w) };
        reinterpret_cast<u16x4*>(xb)[t] = o;
    } else if (b < 4608) {
        __shared__ float tile[32][33];
        int bb = b - 512;
        int bk = bb & 31;        // 1024/32
        int bn = bb >> 5;        // 4096/32
        int k0 = bk * 32, n0 = bn * 32;
        int r = threadIdx.x >> 5, col = threadIdx.x & 31;
#pragma unroll
        for (int it = 0; it < 4; ++it)
            tile[r + it * 8][col] = W[(size_t)(k0 + r + it * 8) * 4096 + n0 + col];
        __syncthreads();
#pragma unroll
        for (int it = 0; it < 4; ++it)
            Wt[(size_t)(n0 + r + it * 8) * 1024 + k0 + col] = f2bf(tile[col][r + it * 8]);
    } else {
        // u,f gates (f32 exact). wave w owns output cols 4w..4w+3
        const int n = b - 4608;
        const int tid = threadIdx.x;
        const int lane = tid & 63, w = tid >> 6;
        const float* xr = x + (size_t)n * 1024;
        float4 p = {0.f, 0.f, 0.f, 0.f};
#pragma unroll
        for (int i = 0; i < 16; ++i) {
            int k = lane + i * 64;
            float xv = xr[k];
            float4 wv = *reinterpret_cast<const float4*>(&Wuf[(size_t)k * 16 + 4 * w]);
            p.x += xv * wv.x; p.y += xv * wv.y; p.z += xv * wv.z; p.w += xv * wv.w;
        }
#pragma unroll
        for (int off = 32; off; off >>= 1) {
            p.x += __shfl_down(p.x, off);
            p.y += __shfl_down(p.y, off);
            p.z += __shfl_down(p.z, off);
            p.w += __shfl_down(p.w, off);
        }
        if (lane == 0) {
#pragma unroll
            for (int t = 0; t < 2; ++t) {
                int h = 2 * w + t;
                float u = (t ? p.z : p.x) + buf[4 * w + 2 * t];
                float f = (t ? p.w : p.y) + buf[4 * w + 2 * t + 1];
                float mp = m_prev[h * 512 + n];
                float m = fmaxf(f + mp, u);
                fe_ue[(h * 512 + n) * 2 + 0] = expf(f + mp - m);
                fe_ue[(h * 512 + n) * 2 + 1] = expf(u - m);
            }
        }
    }
}

// ---- K1: qkvo = x @ W + b  (bf16 MFMA, f32 accum), 64x64 tile ---------------
// global_load_lds(16B) staging, linear LDS, 2-phase double buffer (T3-minimum).
__global__ __launch_bounds__(256) void gemm_qkvo(const unsigned short* __restrict__ A,
                                                 const unsigned short* __restrict__ Bt,
                                                 const float* __restrict__ bias,
                                                 float* __restrict__ C) {
    __shared__ __align__(16) unsigned short As[2][64 * 64];   // 8KB each, row r at r*64
    __shared__ __align__(16) unsigned short Bs[2][64 * 64];
    const int bm = blockIdx.x & 7;          // 512/64 M tiles
    const int bn = blockIdx.x >> 3;         // 4096/64 N tiles
    const int m0 = bm * 64, n0 = bn * 64;
    const int tid = threadIdx.x;
    const int lane = tid & 63, wave = tid >> 6;
    const int wr = wave >> 1, wc = wave & 1;     // 2x2 waves, each 32x32 out
    f32x4 acc[2][2] = {};

    // staging geometry: wave w fills chunks {2w,2w+1}; chunk = 8 rows = 1KB
    const int srow = lane >> 3;          // row within chunk
    const int scol = (lane & 7) * 8;     // k element offset (16B granules)

    // prologue: stage k0=0 into buffer 0
#pragma unroll
    for (int c = 0; c < 2; ++c) {
        int chunk = wave * 2 + c;
        int row = chunk * 8 + srow;
        gll16(A + (size_t)(m0 + row) * 1024 + scol, &As[0][chunk * 512]);
        gll16(Bt + (size_t)(n0 + row) * 1024 + scol, &Bs[0][chunk * 512]);
    }
    __syncthreads();

    int cur = 0;
    for (int t = 0; t < 16; ++t) {
        if (t < 15) {
            int k0 = (t + 1) * 64;
#pragma unroll
            for (int c = 0; c < 2; ++c) {
                int chunk = wave * 2 + c;
                int row = chunk * 8 + srow;
                gll16(A + (size_t)(m0 + row) * 1024 + k0 + scol, &As[cur ^ 1][chunk * 512]);
                gll16(Bt + (size_t)(n0 + row) * 1024 + k0 + scol, &Bs[cur ^ 1][chunk * 512]);
            }
        }
        const unsigned short* as = As[cur];
        const unsigned short* bs = Bs[cur];
        const int row = lane & 15;
        const int kof = (lane >> 4) * 8;
#pragma unroll
        for (int kk = 0; kk < 2; ++kk) {
            int kb = kk * 32 + kof;
            bf16x8 a0 = *reinterpret_cast<const bf16x8*>(&as[(wr * 32 + row) * 64 + kb]);
            bf16x8 a1 = *reinterpret_cast<const bf16x8*>(&as[(wr * 32 + 16 + row) * 64 + kb]);
            bf16x8 b0 = *reinterpret_cast<const bf16x8*>(&bs[(wc * 32 + row) * 64 + kb]);
            bf16x8 b1 = *reinterpret_cast<const bf16x8*>(&bs[(wc * 32 + 16 + row) * 64 + kb]);
            acc[0][0] = __builtin_amdgcn_mfma_f32_16x16x32_bf16(a0, b0, acc[0][0], 0, 0, 0);
            acc[0][1] = __builtin_amdgcn_mfma_f32_16x16x32_bf16(a0, b1, acc[0][1], 0, 0, 0);
            acc[1][0] = __builtin_amdgcn_mfma_f32_16x16x32_bf16(a1, b0, acc[1][0], 0, 0, 0);
            acc[1][1] = __builtin_amdgcn_mfma_f32_16x16x32_bf16(a1, b1, acc[1][1], 0, 0, 0);
        }
        __syncthreads();    // drains this iter's gll (vmcnt0) + protects LDS reuse
        cur ^= 1;
    }

    const int cn = lane & 15, cm = (lane >> 4) * 4;
#pragma unroll
    for (int i = 0; i < 2; ++i)
#pragma unroll
        for (int j = 0; j < 2; ++j) {
            int gm = m0 + wr * 32 + i * 16 + cm;
            int gn = n0 + wc * 32 + j * 16 + cn;
            float b = bias[gn];
#pragma unroll
            for (int v = 0; v < 4; ++v)
                C[(size_t)(gm + v) * 4096 + gn] = acc[i][j][v] + b;
        }
}

// ---- K2: per-(h,n) fused: gates, h-head, c_new stream (non-temporal) --------
__global__ __launch_bounds__(256) void fuse_main(const float* __restrict__ qkvo,
                                                 const float* __restrict__ c_in,
                                                 const float* __restrict__ n_prev,
                                                 const float* __restrict__ fe_ue,
                                                 float* __restrict__ c_out,
                                                 float* __restrict__ hst) {
    const int blk = blockIdx.x;             // 0..4095
    const int h = blk >> 9, n = blk & 511;
    const int tid = threadIdx.x;
    __shared__ float k_s[128], v_s[128];
    __shared__ float rkq[4], rnq[4];

    const float* base = qkvo + (size_t)n * 4096 + h * 512;
    const float fe = fe_ue[(h * 512 + n) * 2 + 0];
    const float ue = fe_ue[(h * 512 + n) * 2 + 1];

    float kq_p = 0.f, nq_p = 0.f;
    if (tid < 128) {
        float q = base[tid];
        float k = base[128 + tid] * KSCALE;
        float v = base[256 + tid];
        k_s[tid] = k;
        v_s[tid] = v;
        float nn = fe * n_prev[(size_t)(h * 512 + n) * 128 + tid] + ue * k;
        kq_p = k * q;
        nq_p = nn * q;
    }
#pragma unroll
    for (int off = 32; off; off >>= 1) {
        kq_p += __shfl_down(kq_p, off);
        nq_p += __shfl_down(nq_p, off);
    }
    if ((tid & 63) == 0) { rkq[tid >> 6] = kq_p; rnq[tid >> 6] = nq_p; }
    __syncthreads();
    const float kq = rkq[0] + rkq[1];
    const float nm = fabsf(rnq[0] + rnq[1]);
    const float g = kq / fmaxf(nm, 1.0f);

    // stream c: 16384 f32 = 4096 f32x4; 16 per thread, non-temporal
    const f32x4* cin4 = reinterpret_cast<const f32x4*>(c_in + (size_t)(h * 512 + n) * 16384);
    f32x4* cout4 = reinterpret_cast<f32x4*>(c_out + (size_t)(h * 512 + n) * 16384);
#pragma unroll
    for (int it = 0; it < 16; ++it) {
        int e4 = tid + it * 256;
        int i = e4 >> 5;
        int j4 = (e4 & 31) * 4;
        f32x4 cv = __builtin_nontemporal_load(&cin4[e4]);
        float uv = ue * v_s[i];
        f32x4 o;
        o.x = fe * cv.x + uv * k_s[j4 + 0];
        o.y = fe * cv.y + uv * k_s[j4 + 1];
        o.z = fe * cv.z + uv * k_s[j4 + 2];
        o.w = fe * cv.w + uv * k_s[j4 + 3];
        __builtin_nontemporal_store(o, &cout4[e4]);
    }

    if (tid < 128) {
        float o = base[384 + tid];
        float sig = 1.f / (1.f + expf(-o));
        hst[(size_t)n * 1024 + h * 128 + tid] = v_s[tid] * g * sig;
    }
}

// ---- K3: residual + LayerNorm -----------------------------------------------
__global__ __launch_bounds__(256) void ln_kernel(const float* __restrict__ x,
                                                 const float* __restrict__ hst,
                                                 float* __restrict__ out) {
    int n = blockIdx.x, tid = threadIdx.x;
    float4 hv = reinterpret_cast<const float4*>(hst + (size_t)n * 1024)[tid];
    float4 xv = reinterpret_cast<const float4*>(x + (size_t)n * 1024)[tid];
    float4 s = { hv.x + xv.x, hv.y + xv.y, hv.z + xv.z, hv.w + xv.w };
    float sum = s.x + s.y + s.z + s.w;
    float sq = s.x * s.x + s.y * s.y + s.z * s.z + s.w * s.w;
#pragma unroll
    for (int off = 32; off; off >>= 1) {
        sum += __shfl_down(sum, off);
        sq += __shfl_down(sq, off);
    }
    __shared__ float rs[4], rq[4];
    if ((tid & 63) == 0) { rs[tid >> 6] = sum; rq[tid >> 6] = sq; }
    __syncthreads();
    sum = rs[0] + rs[1] + rs[2] + rs[3];
    sq = rq[0] + rq[1] + rq[2] + rq[3];
    float mu = sum * (1.f / 1024.f);
    float var = sq * (1.f / 1024.f) - mu * mu;
    float inv = rsqrtf(var + 1e-5f);
    float4 o4 = { (s.x - mu) * inv, (s.y - mu) * inv, (s.z - mu) * inv, (s.w - mu) * inv };
    reinterpret_cast<float4*>(out)[(size_t)n * 256 + tid] = o4;
}

extern "C" void kernel_launch(void* const* d_in, const int* in_sizes, int n_in,
                              void* d_out, int out_size, void* d_ws, size_t ws_size,
                              hipStream_t stream) {
    const float* x      = (const float*)d_in[0];
    const float* c_in   = (const float*)d_in[1];
    const float* m_prev = (const float*)d_in[2];
    const float* n_prev = (const float*)d_in[3];
    const float* Wqkvo  = (const float*)d_in[4];
    const float* bqkvo  = (const float*)d_in[5];
    const float* Wuf    = (const float*)d_in[6];
    const float* buf    = (const float*)d_in[7];
    float* out = (float*)d_out;
    char* ws = (char*)d_ws;

    unsigned short* xb   = (unsigned short*)(ws);                        // 1 MB
    unsigned short* Wt   = (unsigned short*)(ws + (1u << 20));           // 8 MB
    float* qkvo          = (float*)(ws + 9u * (1u << 20));               // 8 MB
    float* fe_ue         = (float*)(ws + 17u * (1u << 20));              // 32 KB
    float* hst           = (float*)(ws + 17u * (1u << 20) + (1u << 16)); // 2 MB

    prep_kernel<<<dim3(5120), dim3(256), 0, stream>>>(x, xb, Wqkvo, Wt, Wuf, buf, m_prev, fe_ue);
    gemm_qkvo  <<<dim3(512),  dim3(256), 0, stream>>>(xb, Wt, bqkvo, qkvo);
    fuse_main  <<<dim3(4096), dim3(256), 0, stream>>>(qkvo, c_in, n_prev, fe_ue, out, hst);
    ln_kernel  <<<dim3(512),  dim3(256), 0, stream>>>(x, hst, out + 67108864ull);
}

// Round 5
// 132.181 us; speedup vs baseline: 1.2176x; 1.0334x over previous
//
#include <hip/hip_runtime.h>
#include <hip/hip_bf16.h>
#include <math.h>

#define KSCALE 0.08838834764831845f  // 1/sqrt(128)

typedef __bf16 bf16x8 __attribute__((ext_vector_type(8)));
typedef float  f32x4  __attribute__((ext_vector_type(4)));
typedef unsigned short u16x4 __attribute__((ext_vector_type(4)));
typedef unsigned short u16x8 __attribute__((ext_vector_type(8)));

__device__ inline unsigned short f2bf(float f) {
    unsigned int u = __float_as_uint(f);
    unsigned int r = (u + 0x7FFFu + ((u >> 16) & 1u)) >> 16;
    return (unsigned short)r;
}

// async global->LDS, 16B per lane; lds dest must be wave-uniform base (+lane*16)
__device__ __forceinline__ void gll16(const unsigned short* g, unsigned short* l) {
    __builtin_amdgcn_global_load_lds(
        (const __attribute__((address_space(1))) unsigned int*)g,
        (__attribute__((address_space(3))) unsigned int*)l,
        16, 0, 0);
}

// ---- K0: fused prep: x->bf16 (0..511), W transpose 64x64 (512..1535), uf (1536..2047)
__global__ __launch_bounds__(256) void prep_kernel(const float* __restrict__ x,
                                                   unsigned short* __restrict__ xb,
                                                   const float* __restrict__ W,
                                                   unsigned short* __restrict__ Wt,
                                                   const float* __restrict__ Wuf,
                                                   const float* __restrict__ buf,
                                                   const float* __restrict__ m_prev,
                                                   float* __restrict__ fe_ue) {
    int b = blockIdx.x;
    const int tid = threadIdx.x;
    if (b < 512) {
        int t = b * 256 + tid;                    // 131072 float4s
        float4 v = reinterpret_cast<const float4*>(x)[t];
        u16x4 o = { f2bf(v.x), f2bf(v.y), f2bf(v.z), f2bf(v.w) };
        reinterpret_cast<u16x4*>(xb)[t] = o;
    } else if (b < 1536) {
        // transpose+convert: W [1024][4096] f32 -> Wt [4096][1024] bf16, 64x64 tiles
        __shared__ unsigned short tile[64][65];
        int bb = b - 512;                  // 0..1023
        int k0 = (bb & 15) * 64;           // 1024/64
        int n0 = (bb >> 4) * 64;           // 4096/64
        int r16 = tid >> 4, c4 = (tid & 15) * 4;
#pragma unroll
        for (int p = 0; p < 4; ++p) {
            int r = p * 16 + r16;
            float4 v = *reinterpret_cast<const float4*>(&W[(size_t)(k0 + r) * 4096 + n0 + c4]);
            tile[r][c4 + 0] = f2bf(v.x);
            tile[r][c4 + 1] = f2bf(v.y);
            tile[r][c4 + 2] = f2bf(v.z);
            tile[r][c4 + 3] = f2bf(v.w);
        }
        __syncthreads();
        int kc = (tid & 7) * 8, r32 = tid >> 3;
#pragma unroll
        for (int p = 0; p < 2; ++p) {
            int rr = p * 32 + r32;
            u16x8 o;
#pragma unroll
            for (int j = 0; j < 8; ++j) o[j] = tile[kc + j][rr];
            *reinterpret_cast<u16x8*>(&Wt[(size_t)(n0 + rr) * 1024 + k0 + kc]) = o;
        }
    } else {
        // u,f gates (f32 exact). wave w owns output cols 4w..4w+3
        const int n = b - 1536;
        const int lane = tid & 63, w = tid >> 6;
        const float* xr = x + (size_t)n * 1024;
        float4 p = {0.f, 0.f, 0.f, 0.f};
#pragma unroll
        for (int i = 0; i < 16; ++i) {
            int k = lane + i * 64;
            float xv = xr[k];
            float4 wv = *reinterpret_cast<const float4*>(&Wuf[(size_t)k * 16 + 4 * w]);
            p.x += xv * wv.x; p.y += xv * wv.y; p.z += xv * wv.z; p.w += xv * wv.w;
        }
#pragma unroll
        for (int off = 32; off; off >>= 1) {
            p.x += __shfl_down(p.x, off);
            p.y += __shfl_down(p.y, off);
            p.z += __shfl_down(p.z, off);
            p.w += __shfl_down(p.w, off);
        }
        if (lane == 0) {
#pragma unroll
            for (int t = 0; t < 2; ++t) {
                int h = 2 * w + t;
                float u = (t ? p.z : p.x) + buf[4 * w + 2 * t];
                float f = (t ? p.w : p.y) + buf[4 * w + 2 * t + 1];
                float mp = m_prev[h * 512 + n];
                float m = fmaxf(f + mp, u);
                fe_ue[(h * 512 + n) * 2 + 0] = expf(f + mp - m);
                fe_ue[(h * 512 + n) * 2 + 1] = expf(u - m);
            }
        }
    }
}

// ---- K1: qkvo = x @ W + b  (bf16 MFMA, f32 accum), 64x64 tile ---------------
// global_load_lds(16B) staging, linear LDS, 2-phase double buffer.
// XCD-affinity mapping: bn = blk&63, bm = blk>>6 -> all 8 blocks sharing a
// B-column-tile sit at stride-64 blockIdx = same XCD = B fetched once per tile.
__global__ __launch_bounds__(256) void gemm_qkvo(const unsigned short* __restrict__ A,
                                                 const unsigned short* __restrict__ Bt,
                                                 const float* __restrict__ bias,
                                                 float* __restrict__ C) {
    __shared__ __align__(16) unsigned short As[2][64 * 64];   // 8KB each, row r at r*64
    __shared__ __align__(16) unsigned short Bs[2][64 * 64];
    const int bn = blockIdx.x & 63;         // 4096/64 N tiles
    const int bm = blockIdx.x >> 6;         // 512/64 M tiles
    const int m0 = bm * 64, n0 = bn * 64;
    const int tid = threadIdx.x;
    const int lane = tid & 63, wave = tid >> 6;
    const int wr = wave >> 1, wc = wave & 1;     // 2x2 waves, each 32x32 out
    f32x4 acc[2][2] = {};

    // staging geometry: wave w fills chunks {2w,2w+1}; chunk = 8 rows = 1KB
    const int srow = lane >> 3;          // row within chunk
    const int scol = (lane & 7) * 8;     // k element offset (16B granules)

    // prologue: stage k0=0 into buffer 0
#pragma unroll
    for (int c = 0; c < 2; ++c) {
        int chunk = wave * 2 + c;
        int row = chunk * 8 + srow;
        gll16(A + (size_t)(m0 + row) * 1024 + scol, &As[0][chunk * 512]);
        gll16(Bt + (size_t)(n0 + row) * 1024 + scol, &Bs[0][chunk * 512]);
    }
    __syncthreads();

    int cur = 0;
    for (int t = 0; t < 16; ++t) {
        if (t < 15) {
            int k0 = (t + 1) * 64;
#pragma unroll
            for (int c = 0; c < 2; ++c) {
                int chunk = wave * 2 + c;
                int row = chunk * 8 + srow;
                gll16(A + (size_t)(m0 + row) * 1024 + k0 + scol, &As[cur ^ 1][chunk * 512]);
                gll16(Bt + (size_t)(n0 + row) * 1024 + k0 + scol, &Bs[cur ^ 1][chunk * 512]);
            }
        }
        const unsigned short* as = As[cur];
        const unsigned short* bs = Bs[cur];
        const int row = lane & 15;
        const int kof = (lane >> 4) * 8;
#pragma unroll
        for (int kk = 0; kk < 2; ++kk) {
            int kb = kk * 32 + kof;
            bf16x8 a0 = *reinterpret_cast<const bf16x8*>(&as[(wr * 32 + row) * 64 + kb]);
            bf16x8 a1 = *reinterpret_cast<const bf16x8*>(&as[(wr * 32 + 16 + row) * 64 + kb]);
            bf16x8 b0 = *reinterpret_cast<const bf16x8*>(&bs[(wc * 32 + row) * 64 + kb]);
            bf16x8 b1 = *reinterpret_cast<const bf16x8*>(&bs[(wc * 32 + 16 + row) * 64 + kb]);
            acc[0][0] = __builtin_amdgcn_mfma_f32_16x16x32_bf16(a0, b0, acc[0][0], 0, 0, 0);
            acc[0][1] = __builtin_amdgcn_mfma_f32_16x16x32_bf16(a0, b1, acc[0][1], 0, 0, 0);
            acc[1][0] = __builtin_amdgcn_mfma_f32_16x16x32_bf16(a1, b0, acc[1][0], 0, 0, 0);
            acc[1][1] = __builtin_amdgcn_mfma_f32_16x16x32_bf16(a1, b1, acc[1][1], 0, 0, 0);
        }
        __syncthreads();    // drains this iter's gll (vmcnt0) + protects LDS reuse
        cur ^= 1;
    }

    const int cn = lane & 15, cm = (lane >> 4) * 4;
#pragma unroll
    for (int i = 0; i < 2; ++i)
#pragma unroll
        for (int j = 0; j < 2; ++j) {
            int gm = m0 + wr * 32 + i * 16 + cm;
            int gn = n0 + wc * 32 + j * 16 + cn;
            float b = bias[gn];
#pragma unroll
            for (int v = 0; v < 4; ++v)
                C[(size_t)(gm + v) * 4096 + gn] = acc[i][j][v] + b;
        }
}

// ---- K2: per-(h,n) fused: gates, h-head, c_new stream (non-temporal) --------
__global__ __launch_bounds__(256) void fuse_main(const float* __restrict__ qkvo,
                                                 const float* __restrict__ c_in,
                                                 const float* __restrict__ n_prev,
                                                 const float* __restrict__ fe_ue,
                                                 float* __restrict__ c_out,
                                                 float* __restrict__ hst) {
    const int blk = blockIdx.x;             // 0..4095
    const int h = blk >> 9, n = blk & 511;
    const int tid = threadIdx.x;
    __shared__ float k_s[128], v_s[128];
    __shared__ float rkq[4], rnq[4];

    const float* base = qkvo + (size_t)n * 4096 + h * 512;
    const float fe = fe_ue[(h * 512 + n) * 2 + 0];
    const float ue = fe_ue[(h * 512 + n) * 2 + 1];

    float kq_p = 0.f, nq_p = 0.f;
    if (tid < 128) {
        float q = base[tid];
        float k = base[128 + tid] * KSCALE;
        float v = base[256 + tid];
        k_s[tid] = k;
        v_s[tid] = v;
        float nn = fe * n_prev[(size_t)(h * 512 + n) * 128 + tid] + ue * k;
        kq_p = k * q;
        nq_p = nn * q;
    }
#pragma unroll
    for (int off = 32; off; off >>= 1) {
        kq_p += __shfl_down(kq_p, off);
        nq_p += __shfl_down(nq_p, off);
    }
    if ((tid & 63) == 0) { rkq[tid >> 6] = kq_p; rnq[tid >> 6] = nq_p; }
    __syncthreads();
    const float kq = rkq[0] + rkq[1];
    const float nm = fabsf(rnq[0] + rnq[1]);
    const float g = kq / fmaxf(nm, 1.0f);

    // stream c: 16384 f32 = 4096 f32x4; 16 per thread, non-temporal
    const f32x4* cin4 = reinterpret_cast<const f32x4*>(c_in + (size_t)(h * 512 + n) * 16384);
    f32x4* cout4 = reinterpret_cast<f32x4*>(c_out + (size_t)(h * 512 + n) * 16384);
#pragma unroll
    for (int it = 0; it < 16; ++it) {
        int e4 = tid + it * 256;
        int i = e4 >> 5;
        int j4 = (e4 & 31) * 4;
        f32x4 cv = __builtin_nontemporal_load(&cin4[e4]);
        float uv = ue * v_s[i];
        f32x4 o;
        o.x = fe * cv.x + uv * k_s[j4 + 0];
        o.y = fe * cv.y + uv * k_s[j4 + 1];
        o.z = fe * cv.z + uv * k_s[j4 + 2];
        o.w = fe * cv.w + uv * k_s[j4 + 3];
        __builtin_nontemporal_store(o, &cout4[e4]);
    }

    if (tid < 128) {
        float o = base[384 + tid];
        float sig = 1.f / (1.f + expf(-o));
        hst[(size_t)n * 1024 + h * 128 + tid] = v_s[tid] * g * sig;
    }
}

// ---- K3: residual + LayerNorm -----------------------------------------------
__global__ __launch_bounds__(256) void ln_kernel(const float* __restrict__ x,
                                                 const float* __restrict__ hst,
                                                 float* __restrict__ out) {
    int n = blockIdx.x, tid = threadIdx.x;
    float4 hv = reinterpret_cast<const float4*>(hst + (size_t)n * 1024)[tid];
    float4 xv = reinterpret_cast<const float4*>(x + (size_t)n * 1024)[tid];
    float4 s = { hv.x + xv.x, hv.y + xv.y, hv.z + xv.z, hv.w + xv.w };
    float sum = s.x + s.y + s.z + s.w;
    float sq = s.x * s.x + s.y * s.y + s.z * s.z + s.w * s.w;
#pragma unroll
    for (int off = 32; off; off >>= 1) {
        sum += __shfl_down(sum, off);
        sq += __shfl_down(sq, off);
    }
    __shared__ float rs[4], rq[4];
    if ((tid & 63) == 0) { rs[tid >> 6] = sum; rq[tid >> 6] = sq; }
    __syncthreads();
    sum = rs[0] + rs[1] + rs[2] + rs[3];
    sq = rq[0] + rq[1] + rq[2] + rq[3];
    float mu = sum * (1.f / 1024.f);
    float var = sq * (1.f / 1024.f) - mu * mu;
    float inv = rsqrtf(var + 1e-5f);
    float4 o4 = { (s.x - mu) * inv, (s.y - mu) * inv, (s.z - mu) * inv, (s.w - mu) * inv };
    reinterpret_cast<float4*>(out)[(size_t)n * 256 + tid] = o4;
}

extern "C" void kernel_launch(void* const* d_in, const int* in_sizes, int n_in,
                              void* d_out, int out_size, void* d_ws, size_t ws_size,
                              hipStream_t stream) {
    const float* x      = (const float*)d_in[0];
    const float* c_in   = (const float*)d_in[1];
    const float* m_prev = (const float*)d_in[2];
    const float* n_prev = (const float*)d_in[3];
    const float* Wqkvo  = (const float*)d_in[4];
    const float* bqkvo  = (const float*)d_in[5];
    const float* Wuf    = (const float*)d_in[6];
    const float* buf    = (const float*)d_in[7];
    float* out = (float*)d_out;
    char* ws = (char*)d_ws;

    unsigned short* xb   = (unsigned short*)(ws);                        // 1 MB
    unsigned short* Wt   = (unsigned short*)(ws + (1u << 20));           // 8 MB
    float* qkvo          = (float*)(ws + 9u * (1u << 20));               // 8 MB
    float* fe_ue         = (float*)(ws + 17u * (1u << 20));              // 32 KB
    float* hst           = (float*)(ws + 17u * (1u << 20) + (1u << 16)); // 2 MB

    prep_kernel<<<dim3(2048), dim3(256), 0, stream>>>(x, xb, Wqkvo, Wt, Wuf, buf, m_prev, fe_ue);
    gemm_qkvo  <<<dim3(512),  dim3(256), 0, stream>>>(xb, Wt, bqkvo, qkvo);
    fuse_main  <<<dim3(4096), dim3(256), 0, stream>>>(qkvo, c_in, n_prev, fe_ue, out, hst);
    ln_kernel  <<<dim3(512),  dim3(256), 0, stream>>>(x, hst, out + 67108864ull);
}